// Round 16
// baseline (2625.573 us; speedup 1.0000x reference)
//
#include <hip/hip_runtime.h>
#include <hip/hip_bf16.h>
#include <math.h>

constexpr int NN  = 100000;   // nodes
constexpr int EE  = 3200000;  // edges
constexpr int HID = 128;
constexpr int NG  = 512;      // 4*HID
constexpr int NOUT = 64;
constexpr int HOPS = 10;
constexpr int SCAN_BLK = 1024;
constexpr int NBLK_SCAN = (NN + SCAN_BLK - 1) / SCAN_BLK;   // 98
constexpr int NTILE = NN / 32;                              // 3125 row-tiles
constexpr int PERSIST = 256;                                // 1 block/CU
constexpr size_t CPERM_SLOTS = (size_t)NTILE * 4 * 2 * 2 * 64;  // half4 slots

typedef __attribute__((ext_vector_type(8))) short short8;
typedef __attribute__((ext_vector_type(4))) float f32x4;
typedef __attribute__((ext_vector_type(4))) _Float16 half4;
typedef unsigned long long ull;

__device__ __forceinline__ ushort f2bf(float f) {
    uint u = __builtin_bit_cast(uint, f);
    u += 0x7fff + ((u >> 16) & 1);          // RNE
    return (ushort)(u >> 16);
}
__device__ __forceinline__ float bflo(uint u) { return __builtin_bit_cast(float, u << 16); }
__device__ __forceinline__ float bfhi(uint u) { return __builtin_bit_cast(float, u & 0xffff0000u); }

__device__ __forceinline__ float sigf(float v) { return 1.0f / (1.0f + __expf(-v)); }
__device__ __forceinline__ float tanh_fast(float x) {
    float t = __expf(-2.0f * fabsf(x));
    float r = (1.0f - t) / (1.0f + t);
    return copysignf(r, x);
}

__device__ __forceinline__ short8 load_frag(const ushort* p) {
    return *reinterpret_cast<const short8*>(p);
}
__device__ __forceinline__ f32x4 mfma16(short8 a, short8 b, f32x4 c) {
    return __builtin_amdgcn_mfma_f32_16x16x32_bf16(a, b, c, 0, 0, 0);
}

// ---------------------------------------------------------------------------
// fp32 -> bf16 conversion (vectorized), n4 = n/4
// ---------------------------------------------------------------------------
__global__ __launch_bounds__(256) void convert_bf16_kernel(
    const float* __restrict__ src, ushort* __restrict__ dst, int n4)
{
    int i = blockIdx.x * 256 + threadIdx.x;
    if (i < n4) {
        float4 v = reinterpret_cast<const float4*>(src)[i];
        ushort4 o;
        o.x = f2bf(v.x); o.y = f2bf(v.y); o.z = f2bf(v.z); o.w = f2bf(v.w);
        reinterpret_cast<ushort4*>(dst)[i] = o;
    }
}

__global__ __launch_bounds__(256) void bsum_kernel(
    const float* __restrict__ bih, const float* __restrict__ bhh, float* __restrict__ bsum)
{
    int i = blockIdx.x * 256 + threadIdx.x;
    if (i < NG) bsum[i] = bih[i] + bhh[i];
}

// ---------------------------------------------------------------------------
// CSR build: histogram -> 3-stage scan -> packed scatter
// ---------------------------------------------------------------------------
__global__ __launch_bounds__(256) void hist_kernel(const int* __restrict__ erow,
                                                   int* __restrict__ deg)
{
    int e = blockIdx.x * 256 + threadIdx.x;
    atomicAdd(&deg[erow[e]], 1);
}

__global__ __launch_bounds__(SCAN_BLK) void scan1_kernel(const int* __restrict__ deg,
                                                         int* __restrict__ bsums)
{
    __shared__ int tmp[SCAN_BLK];
    int t = threadIdx.x;
    int i = blockIdx.x * SCAN_BLK + t;
    tmp[t] = (i < NN) ? deg[i] : 0;
    __syncthreads();
    for (int off = SCAN_BLK / 2; off > 0; off >>= 1) {
        if (t < off) tmp[t] += tmp[t + off];
        __syncthreads();
    }
    if (t == 0) bsums[blockIdx.x] = tmp[0];
}

__global__ __launch_bounds__(128) void scan2_kernel(int* __restrict__ bsums)
{
    __shared__ int tmp[128];
    int t = threadIdx.x;
    tmp[t] = (t < NBLK_SCAN) ? bsums[t] : 0;
    __syncthreads();
    for (int off = 1; off < 128; off <<= 1) {
        int add = (t >= off) ? tmp[t - off] : 0;
        __syncthreads();
        tmp[t] += add;
        __syncthreads();
    }
    if (t < NBLK_SCAN) bsums[t] = (t == 0) ? 0 : tmp[t - 1];
}

__global__ __launch_bounds__(SCAN_BLK) void scan3_kernel(const int* __restrict__ deg,
                                                         const int* __restrict__ bsums,
                                                         int* __restrict__ rp,
                                                         int* __restrict__ cur)
{
    __shared__ int tmp[SCAN_BLK];
    int t = threadIdx.x;
    int i = blockIdx.x * SCAN_BLK + t;
    int v = (i < NN) ? deg[i] : 0;
    tmp[t] = v;
    __syncthreads();
    for (int off = 1; off < SCAN_BLK; off <<= 1) {
        int add = (t >= off) ? tmp[t - off] : 0;
        __syncthreads();
        tmp[t] += add;
        __syncthreads();
    }
    int incl = tmp[t] + bsums[blockIdx.x];
    if (i < NN) {
        rp[i + 1] = incl;
        cur[i] = incl - v;
    }
    if (i == 0) rp[0] = 0;
}

__global__ __launch_bounds__(256) void scatter_kernel(
    const int* __restrict__ erow, const int* __restrict__ ecol,
    const float* __restrict__ eval, int* __restrict__ cur,
    ull* __restrict__ epack)
{
    int e = blockIdx.x * 256 + threadIdx.x;
    int r = erow[e];
    int p = atomicAdd(&cur[r], 1);
    ull pk = (ull)(uint)ecol[e] |
             ((ull)__builtin_bit_cast(uint, eval[e]) << 32);
    __builtin_nontemporal_store(pk, epack + p);
}

// ---------------------------------------------------------------------------
// Persistent-weight fused LSTM cell (r14): 256 blocks (1/CU), 4 waves.
// Wave w holds its mod-4 gate quarter of W_ih AND W_hh in registers; grid-
// strides over 3125 32-row tiles. x/h fragments co-issued. c state fp16.
// ---------------------------------------------------------------------------
template<bool FIRST>
__global__ __launch_bounds__(256, 1) void cell_kernel(
    const ushort* __restrict__ xb, const ushort* __restrict__ hb,
    const ushort* __restrict__ Wib, const ushort* __restrict__ Whb,
    const float* __restrict__ bsum, half4* __restrict__ cperm,
    ushort* __restrict__ hout)
{
    __shared__ __align__(16) ushort lds_h[32 * 136];

    const int t  = threadIdx.x;
    const int l  = t & 63;
    const int w  = t >> 6;
    const int lr = l & 15;
    const int lk = l >> 4;

    // one-time: weight quarters into registers
    short8 wi[8][4], wh[8][4];
#pragma unroll
    for (int nI = 0; nI < 8; ++nI) {
        const size_t wb = (size_t)((4 * nI + w) * 16 + lr) * HID + lk * 8;
#pragma unroll
        for (int ks = 0; ks < 4; ++ks) {
            wi[nI][ks] = load_frag(Wib + wb + ks * 32);
            if (!FIRST) wh[nI][ks] = load_frag(Whb + wb + ks * 32);
        }
    }
    float bs[8];
#pragma unroll
    for (int nI = 0; nI < 8; ++nI) bs[nI] = bsum[(4 * nI + w) * 16 + lr];

    for (int tile = blockIdx.x; tile < NTILE; tile += PERSIST) {
        const int row0 = tile * 32;

        f32x4 acc[8][2];
#pragma unroll
        for (int nI = 0; nI < 8; ++nI) {
            acc[nI][0] = f32x4{bs[nI], bs[nI], bs[nI], bs[nI]};
            acc[nI][1] = acc[nI][0];
        }

        // co-issue all A-fragment loads (x and h) -> one latency window
        short8 ax[2][4], ah[2][4];
#pragma unroll
        for (int rf = 0; rf < 2; ++rf) {
            const size_t ab = (size_t)(row0 + rf * 16 + lr) * HID + lk * 8;
#pragma unroll
            for (int ks = 0; ks < 4; ++ks) {
                ax[rf][ks] = load_frag(xb + ab + ks * 32);
                if (!FIRST) ah[rf][ks] = load_frag(hb + ab + ks * 32);
            }
        }
        // pass 1: x @ W_ih^T
#pragma unroll
        for (int nI = 0; nI < 8; ++nI)
#pragma unroll
            for (int rf = 0; rf < 2; ++rf)
#pragma unroll
                for (int ks = 0; ks < 4; ++ks)
                    acc[nI][rf] = mfma16(ax[rf][ks], wi[nI][ks], acc[nI][rf]);
        // pass 2: h @ W_hh^T
        if (!FIRST) {
#pragma unroll
            for (int nI = 0; nI < 8; ++nI)
#pragma unroll
                for (int rf = 0; rf < 2; ++rf)
#pragma unroll
                    for (int ks = 0; ks < 4; ++ks)
                        acc[nI][rf] = mfma16(ah[rf][ks], wh[nI][ks], acc[nI][rf]);
        }

        __syncthreads();   // lds_h reuse guard (prev tile's reads done)

        // epilogue: LSTM elementwise; c fp16 permuted, h via LDS transpose
#pragma unroll
        for (int nj = 0; nj < 2; ++nj) {
            const int col = (w + 4 * nj) * 16 + lr;
#pragma unroll
            for (int rf = 0; rf < 2; ++rf) {
                f32x4 iv = acc[nj][rf];
                f32x4 fv = acc[nj + 2][rf];
                f32x4 gv = acc[nj + 4][rf];
                f32x4 ov = acc[nj + 6][rf];
                const size_t cidx = ((((size_t)tile * 4 + w) * 2 + nj) * 2 + rf) * 64 + l;
                float cold[4];
                if (FIRST) {
                    cold[0] = cold[1] = cold[2] = cold[3] = 0.f;
                } else {
                    half4 ch = cperm[cidx];
#pragma unroll
                    for (int jj = 0; jj < 4; ++jj) cold[jj] = (float)ch[jj];
                }
                half4 cw;
                float hn[4];
#pragma unroll
                for (int jj = 0; jj < 4; ++jj) {
                    float c2 = sigf(fv[jj]) * cold[jj] + sigf(iv[jj]) * tanh_fast(gv[jj]);
                    cw[jj] = (_Float16)c2;
                    hn[jj] = sigf(ov[jj]) * tanh_fast(c2);
                }
                cperm[cidx] = cw;
                const int rbase = rf * 16 + lk * 4;
#pragma unroll
                for (int jj = 0; jj < 4; ++jj)
                    lds_h[(rbase + jj) * 136 + col] = f2bf(hn[jj]);
            }
        }
        __syncthreads();
        // coalesced h store: thread t moves 16 ushorts: row t>>3, cols (t&7)*16..+15
        {
            const ushort* lsrc = &lds_h[(t >> 3) * 136 + (t & 7) * 16];
            short8 v0 = *reinterpret_cast<const short8*>(lsrc);
            short8 v1 = *reinterpret_cast<const short8*>(lsrc + 8);
            ushort* gdst = hout + (size_t)row0 * HID + t * 16;
            *reinterpret_cast<short8*>(gdst) = v0;
            *reinterpret_cast<short8*>(gdst + 8) = v1;
        }
    }
}

// ---------------------------------------------------------------------------
// SpMM: one wave per row, lane owns 2 features (dword gather), 16-edge-deep
// MLP (16 loads + 16 gathers in flight), nontemporal edge stream.
// ---------------------------------------------------------------------------
__global__ __launch_bounds__(256) void spmm_kernel(
    const int* __restrict__ rp, const ull* __restrict__ epack,
    const ushort* __restrict__ hin, ushort* __restrict__ hout)
{
    int r = blockIdx.x * 4 + (threadIdx.x >> 6);
    if (r >= NN) return;
    int l = threadIdx.x & 63;
    int beg = rp[r], end = rp[r + 1];
    const ushort* hbase = hin + l * 2;

    float s0[8] = {0.f, 0.f, 0.f, 0.f, 0.f, 0.f, 0.f, 0.f};
    float s1[8] = {0.f, 0.f, 0.f, 0.f, 0.f, 0.f, 0.f, 0.f};

    int e = beg;
    for (; e + 16 <= end; e += 16) {
        ull u[16];
#pragma unroll
        for (int k = 0; k < 16; ++k) u[k] = __builtin_nontemporal_load(epack + e + k);
        uint g[16];
#pragma unroll
        for (int k = 0; k < 16; ++k)
            g[k] = *reinterpret_cast<const uint*>(hbase + (size_t)(uint)u[k] * HID);
#pragma unroll
        for (int k = 0; k < 16; ++k) {
            float v = __builtin_bit_cast(float, (uint)(u[k] >> 32));
            s0[k & 7] += v * bflo(g[k]);
            s1[k & 7] += v * bfhi(g[k]);
        }
    }
    for (; e + 8 <= end; e += 8) {
        ull u[8];
#pragma unroll
        for (int k = 0; k < 8; ++k) u[k] = __builtin_nontemporal_load(epack + e + k);
        uint g[8];
#pragma unroll
        for (int k = 0; k < 8; ++k)
            g[k] = *reinterpret_cast<const uint*>(hbase + (size_t)(uint)u[k] * HID);
#pragma unroll
        for (int k = 0; k < 8; ++k) {
            float v = __builtin_bit_cast(float, (uint)(u[k] >> 32));
            s0[k] += v * bflo(g[k]);
            s1[k] += v * bfhi(g[k]);
        }
    }
    for (; e + 4 <= end; e += 4) {
        ull u[4];
#pragma unroll
        for (int k = 0; k < 4; ++k) u[k] = __builtin_nontemporal_load(epack + e + k);
        uint g[4];
#pragma unroll
        for (int k = 0; k < 4; ++k)
            g[k] = *reinterpret_cast<const uint*>(hbase + (size_t)(uint)u[k] * HID);
#pragma unroll
        for (int k = 0; k < 4; ++k) {
            float v = __builtin_bit_cast(float, (uint)(u[k] >> 32));
            s0[k] += v * bflo(g[k]);
            s1[k] += v * bfhi(g[k]);
        }
    }
    for (; e < end; ++e) {
        ull u0 = __builtin_nontemporal_load(epack + e);
        float v0 = __builtin_bit_cast(float, (uint)(u0 >> 32));
        uint g0 = *reinterpret_cast<const uint*>(hbase + (size_t)(uint)u0 * HID);
        s0[0] += v0 * bflo(g0);
        s1[0] += v0 * bfhi(g0);
    }
    float a0 = ((s0[0] + s0[1]) + (s0[2] + s0[3])) + ((s0[4] + s0[5]) + (s0[6] + s0[7]));
    float a1 = ((s1[0] + s1[1]) + (s1[2] + s1[3])) + ((s1[4] + s1[5]) + (s1[6] + s1[7]));
    uint o = ((uint)f2bf(a1) << 16) | (uint)f2bf(a0);
    *reinterpret_cast<uint*>(hout + (size_t)r * HID + l * 2) = o;
}

// ---------------------------------------------------------------------------
// final: out = relu(h) @ fc_w^T + fc_b  (MFMA)
// ---------------------------------------------------------------------------
__global__ __launch_bounds__(256) void final_mfma_kernel(
    const ushort* __restrict__ hb, const ushort* __restrict__ fcwb,
    const float* __restrict__ fcb, float* __restrict__ out)
{
    const int t = threadIdx.x;
    const int l = t & 63;
    const int w = t >> 6;
    const int lr = l & 15;
    const int lk = l >> 4;
    const int row0 = blockIdx.x * 64 + w * 16;

    f32x4 acc[4];
#pragma unroll
    for (int n = 0; n < 4; ++n) {
        float b = fcb[n * 16 + lr];
        acc[n] = f32x4{b, b, b, b};
    }

    const short8 z8 = {0, 0, 0, 0, 0, 0, 0, 0};
    const int arow = row0 + lr;
    const bool aok = arow < NN;
    short8 a[4];
#pragma unroll
    for (int ks = 0; ks < 4; ++ks) {
        short8 v = aok ? load_frag(hb + (size_t)arow * HID + ks * 32 + lk * 8) : z8;
#pragma unroll
        for (int i = 0; i < 8; ++i) {
            ushort u = (ushort)v[i];
            if (u & 0x8000) v[i] = 0;   // relu in bf16
        }
        a[ks] = v;
    }

#pragma unroll
    for (int n = 0; n < 4; ++n) {
        const ushort* wp = fcwb + (size_t)(n * 16 + lr) * HID + lk * 8;
#pragma unroll
        for (int ks = 0; ks < 4; ++ks)
            acc[n] = mfma16(a[ks], load_frag(wp + ks * 32), acc[n]);
    }

#pragma unroll
    for (int n = 0; n < 4; ++n) {
#pragma unroll
        for (int j = 0; j < 4; ++j) {
            int row = row0 + lk * 4 + j;
            if (row < NN) out[(size_t)row * NOUT + n * 16 + lr] = acc[n][j];
        }
    }
}

// ---------------------------------------------------------------------------
extern "C" void kernel_launch(void* const* d_in, const int* in_sizes, int n_in,
                              void* d_out, int out_size, void* d_ws, size_t ws_size,
                              hipStream_t stream)
{
    const float* x    = (const float*)d_in[0];
    const int*   erow = (const int*)d_in[1];
    const int*   ecol = (const int*)d_in[2];
    const float* eval = (const float*)d_in[3];
    const float* Wih  = (const float*)d_in[4];
    const float* Whh  = (const float*)d_in[5];
    const float* bih  = (const float*)d_in[6];
    const float* bhh  = (const float*)d_in[7];
    const float* fcw  = (const float*)d_in[8];
    const float* fcb  = (const float*)d_in[9];
    float* out = (float*)d_out;

    char* ws = (char*)d_ws;
    size_t off = 0;
    auto alloc = [&](size_t bytes) -> void* {
        void* p = ws + off;
        off = (off + bytes + 255) & ~(size_t)255;
        return p;
    };
    ushort* hb_a  = (ushort*)alloc((size_t)NN * HID * 2);
    ushort* hb_b  = (ushort*)alloc((size_t)NN * HID * 2);
    half4*  cperm = (half4*)alloc(CPERM_SLOTS * 8);
    ushort* xb    = (ushort*)alloc((size_t)NN * HID * 2);
    ushort* Wib   = (ushort*)alloc((size_t)NG * HID * 2);
    ushort* Whb   = (ushort*)alloc((size_t)NG * HID * 2);
    ushort* fcwb  = (ushort*)alloc((size_t)NOUT * HID * 2);
    float*  bsum  = (float*)alloc((size_t)NG * 4);
    int*    rp    = (int*)alloc((size_t)(NN + 1) * 4);
    int*    deg   = (int*)alloc((size_t)NN * 4);
    int*    cur   = (int*)alloc((size_t)NN * 4);
    int*    bsums = (int*)alloc((size_t)NBLK_SCAN * 4);
    ull*    epack = (ull*)alloc((size_t)EE * 8);
    (void)ws_size;

    // conversions to bf16
    convert_bf16_kernel<<<(NN * HID / 4 + 255) / 256, 256, 0, stream>>>(x, xb, NN * HID / 4);
    convert_bf16_kernel<<<(NG * HID / 4 + 255) / 256, 256, 0, stream>>>(Wih, Wib, NG * HID / 4);
    convert_bf16_kernel<<<(NG * HID / 4 + 255) / 256, 256, 0, stream>>>(Whh, Whb, NG * HID / 4);
    convert_bf16_kernel<<<(NOUT * HID / 4 + 255) / 256, 256, 0, stream>>>(fcw, fcwb, NOUT * HID / 4);
    bsum_kernel<<<2, 256, 0, stream>>>(bih, bhh, bsum);

    // CSR build
    hipMemsetAsync(deg, 0, (size_t)NN * 4, stream);
    hist_kernel<<<EE / 256, 256, 0, stream>>>(erow, deg);
    scan1_kernel<<<NBLK_SCAN, SCAN_BLK, 0, stream>>>(deg, bsums);
    scan2_kernel<<<1, 128, 0, stream>>>(bsums);
    scan3_kernel<<<NBLK_SCAN, SCAN_BLK, 0, stream>>>(deg, bsums, rp, cur);
    scatter_kernel<<<EE / 256, 256, 0, stream>>>(erow, ecol, eval, cur, epack);

    const int SPMM_GRID = NN / 4;          // 25000

    cell_kernel<true><<<PERSIST, 256, 0, stream>>>(xb, hb_b, Wib, Whb, bsum, cperm, hb_a);
    spmm_kernel<<<SPMM_GRID, 256, 0, stream>>>(rp, epack, hb_a, hb_b);
    for (int hop = 1; hop < HOPS; ++hop) {
        cell_kernel<false><<<PERSIST, 256, 0, stream>>>(xb, hb_b, Wib, Whb, bsum, cperm, hb_a);
        spmm_kernel<<<SPMM_GRID, 256, 0, stream>>>(rp, epack, hb_a, hb_b);
    }

    final_mfma_kernel<<<(NN + 63) / 64, 256, 0, stream>>>(hb_b, fcwb, fcb, out);
}

// Round 17
// 2465.790 us; speedup vs baseline: 1.0648x; 1.0648x over previous
//
#include <hip/hip_runtime.h>
#include <hip/hip_bf16.h>
#include <math.h>

constexpr int NN  = 100000;   // nodes
constexpr int EE  = 3200000;  // edges
constexpr int HID = 128;
constexpr int NG  = 512;      // 4*HID
constexpr int NOUT = 64;
constexpr int HOPS = 10;
constexpr int SCAN_BLK = 1024;
constexpr int NBLK_SCAN = (NN + SCAN_BLK - 1) / SCAN_BLK;   // 98
constexpr int NTILE = NN / 32;                              // 3125 row-tiles
constexpr int PERSIST = 256;                                // 1 block/CU
constexpr size_t CPERM_SLOTS = (size_t)NTILE * 4 * 2 * 2 * 64;  // half4 slots

typedef __attribute__((ext_vector_type(8))) short short8;
typedef __attribute__((ext_vector_type(4))) float f32x4;
typedef __attribute__((ext_vector_type(4))) _Float16 half4;
typedef unsigned long long ull;

__device__ __forceinline__ ushort f2bf(float f) {
    uint u = __builtin_bit_cast(uint, f);
    u += 0x7fff + ((u >> 16) & 1);          // RNE
    return (ushort)(u >> 16);
}
__device__ __forceinline__ float bflo(uint u) { return __builtin_bit_cast(float, u << 16); }
__device__ __forceinline__ float bfhi(uint u) { return __builtin_bit_cast(float, u & 0xffff0000u); }

__device__ __forceinline__ float sigf(float v) { return 1.0f / (1.0f + __expf(-v)); }
__device__ __forceinline__ float tanh_fast(float x) {
    float t = __expf(-2.0f * fabsf(x));
    float r = (1.0f - t) / (1.0f + t);
    return copysignf(r, x);
}

__device__ __forceinline__ short8 load_frag(const ushort* p) {
    return *reinterpret_cast<const short8*>(p);
}
__device__ __forceinline__ f32x4 mfma16(short8 a, short8 b, f32x4 c) {
    return __builtin_amdgcn_mfma_f32_16x16x32_bf16(a, b, c, 0, 0, 0);
}

// ---------------------------------------------------------------------------
// fp32 -> bf16 conversion (vectorized), n4 = n/4
// ---------------------------------------------------------------------------
__global__ __launch_bounds__(256) void convert_bf16_kernel(
    const float* __restrict__ src, ushort* __restrict__ dst, int n4)
{
    int i = blockIdx.x * 256 + threadIdx.x;
    if (i < n4) {
        float4 v = reinterpret_cast<const float4*>(src)[i];
        ushort4 o;
        o.x = f2bf(v.x); o.y = f2bf(v.y); o.z = f2bf(v.z); o.w = f2bf(v.w);
        reinterpret_cast<ushort4*>(dst)[i] = o;
    }
}

__global__ __launch_bounds__(256) void bsum_kernel(
    const float* __restrict__ bih, const float* __restrict__ bhh, float* __restrict__ bsum)
{
    int i = blockIdx.x * 256 + threadIdx.x;
    if (i < NG) bsum[i] = bih[i] + bhh[i];
}

// ---------------------------------------------------------------------------
// CSR build: histogram -> 3-stage scan -> packed scatter
// ---------------------------------------------------------------------------
__global__ __launch_bounds__(256) void hist_kernel(const int* __restrict__ erow,
                                                   int* __restrict__ deg)
{
    int e = blockIdx.x * 256 + threadIdx.x;
    atomicAdd(&deg[erow[e]], 1);
}

__global__ __launch_bounds__(SCAN_BLK) void scan1_kernel(const int* __restrict__ deg,
                                                         int* __restrict__ bsums)
{
    __shared__ int tmp[SCAN_BLK];
    int t = threadIdx.x;
    int i = blockIdx.x * SCAN_BLK + t;
    tmp[t] = (i < NN) ? deg[i] : 0;
    __syncthreads();
    for (int off = SCAN_BLK / 2; off > 0; off >>= 1) {
        if (t < off) tmp[t] += tmp[t + off];
        __syncthreads();
    }
    if (t == 0) bsums[blockIdx.x] = tmp[0];
}

__global__ __launch_bounds__(128) void scan2_kernel(int* __restrict__ bsums)
{
    __shared__ int tmp[128];
    int t = threadIdx.x;
    tmp[t] = (t < NBLK_SCAN) ? bsums[t] : 0;
    __syncthreads();
    for (int off = 1; off < 128; off <<= 1) {
        int add = (t >= off) ? tmp[t - off] : 0;
        __syncthreads();
        tmp[t] += add;
        __syncthreads();
    }
    if (t < NBLK_SCAN) bsums[t] = (t == 0) ? 0 : tmp[t - 1];
}

__global__ __launch_bounds__(SCAN_BLK) void scan3_kernel(const int* __restrict__ deg,
                                                         const int* __restrict__ bsums,
                                                         int* __restrict__ rp,
                                                         int* __restrict__ cur)
{
    __shared__ int tmp[SCAN_BLK];
    int t = threadIdx.x;
    int i = blockIdx.x * SCAN_BLK + t;
    int v = (i < NN) ? deg[i] : 0;
    tmp[t] = v;
    __syncthreads();
    for (int off = 1; off < SCAN_BLK; off <<= 1) {
        int add = (t >= off) ? tmp[t - off] : 0;
        __syncthreads();
        tmp[t] += add;
        __syncthreads();
    }
    int incl = tmp[t] + bsums[blockIdx.x];
    if (i < NN) {
        rp[i + 1] = incl;
        cur[i] = incl - v;
    }
    if (i == 0) rp[0] = 0;
}

__global__ __launch_bounds__(256) void scatter_kernel(
    const int* __restrict__ erow, const int* __restrict__ ecol,
    const float* __restrict__ eval, int* __restrict__ cur,
    ull* __restrict__ epack)
{
    int e = blockIdx.x * 256 + threadIdx.x;
    int r = erow[e];
    int p = atomicAdd(&cur[r], 1);
    ull pk = (ull)(uint)ecol[e] |
             ((ull)__builtin_bit_cast(uint, eval[e]) << 32);
    __builtin_nontemporal_store(pk, epack + p);
}

// ---------------------------------------------------------------------------
// Persistent-weight fused LSTM cell, cross-tile software pipeline:
// ax regs die after pass-1 -> refill with NEXT tile's x during pass-2;
// ah regs die after pass-2 -> refill with NEXT tile's h during epilogue.
// Zero extra registers; loads hide under MFMA/VALU issue. c state fp16.
// 256 blocks (1/CU), 4 waves; wave w owns mod-4 gate quarter in registers.
// ---------------------------------------------------------------------------
template<bool FIRST>
__global__ __launch_bounds__(256, 1) void cell_kernel(
    const ushort* __restrict__ xb, const ushort* __restrict__ hb,
    const ushort* __restrict__ Wib, const ushort* __restrict__ Whb,
    const float* __restrict__ bsum, half4* __restrict__ cperm,
    ushort* __restrict__ hout)
{
    __shared__ __align__(16) ushort lds_h[32 * 136];

    const int t  = threadIdx.x;
    const int l  = t & 63;
    const int w  = t >> 6;
    const int lr = l & 15;
    const int lk = l >> 4;

    // one-time: weight quarters into registers
    short8 wi[8][4], wh[8][4];
#pragma unroll
    for (int nI = 0; nI < 8; ++nI) {
        const size_t wb = (size_t)((4 * nI + w) * 16 + lr) * HID + lk * 8;
#pragma unroll
        for (int ks = 0; ks < 4; ++ks) {
            wi[nI][ks] = load_frag(Wib + wb + ks * 32);
            if (!FIRST) wh[nI][ks] = load_frag(Whb + wb + ks * 32);
        }
    }
    float bs[8];
#pragma unroll
    for (int nI = 0; nI < 8; ++nI) bs[nI] = bsum[(4 * nI + w) * 16 + lr];

    const size_t lane_off = (size_t)lr * HID + lk * 8;

    // preload tile0's fragments
    short8 ax[2][4], ah[2][4];
    {
        const size_t r0 = (size_t)blockIdx.x * 32 * HID + lane_off;
#pragma unroll
        for (int rf = 0; rf < 2; ++rf)
#pragma unroll
            for (int ks = 0; ks < 4; ++ks) {
                ax[rf][ks] = load_frag(xb + r0 + (size_t)rf * 16 * HID + ks * 32);
                if (!FIRST) ah[rf][ks] = load_frag(hb + r0 + (size_t)rf * 16 * HID + ks * 32);
            }
    }

    for (int tile = blockIdx.x; tile < NTILE; tile += PERSIST) {
        const int row0 = tile * 32;
        const int ntile = (tile + PERSIST < NTILE) ? tile + PERSIST : tile;
        const size_t nb = (size_t)ntile * 32 * HID + lane_off;

        f32x4 acc[8][2];
#pragma unroll
        for (int nI = 0; nI < 8; ++nI) {
            acc[nI][0] = f32x4{bs[nI], bs[nI], bs[nI], bs[nI]};
            acc[nI][1] = acc[nI][0];
        }

        // pass 1: x @ W_ih^T
#pragma unroll
        for (int nI = 0; nI < 8; ++nI)
#pragma unroll
            for (int rf = 0; rf < 2; ++rf)
#pragma unroll
                for (int ks = 0; ks < 4; ++ks)
                    acc[nI][rf] = mfma16(ax[rf][ks], wi[nI][ks], acc[nI][rf]);

        // refill ax with NEXT tile's x (overlaps pass-2 MFMA issue)
#pragma unroll
        for (int rf = 0; rf < 2; ++rf)
#pragma unroll
            for (int ks = 0; ks < 4; ++ks)
                ax[rf][ks] = load_frag(xb + nb + (size_t)rf * 16 * HID + ks * 32);

        // pass 2: h @ W_hh^T
        if (!FIRST) {
#pragma unroll
            for (int nI = 0; nI < 8; ++nI)
#pragma unroll
                for (int rf = 0; rf < 2; ++rf)
#pragma unroll
                    for (int ks = 0; ks < 4; ++ks)
                        acc[nI][rf] = mfma16(ah[rf][ks], wh[nI][ks], acc[nI][rf]);

            // refill ah with NEXT tile's h (overlaps epilogue VALU)
#pragma unroll
            for (int rf = 0; rf < 2; ++rf)
#pragma unroll
                for (int ks = 0; ks < 4; ++ks)
                    ah[rf][ks] = load_frag(hb + nb + (size_t)rf * 16 * HID + ks * 32);
        }

        __syncthreads();   // lds_h reuse guard (prev tile's reads done)

        // epilogue: LSTM elementwise; c fp16 permuted, h via LDS transpose
#pragma unroll
        for (int nj = 0; nj < 2; ++nj) {
            const int col = (w + 4 * nj) * 16 + lr;
#pragma unroll
            for (int rf = 0; rf < 2; ++rf) {
                f32x4 iv = acc[nj][rf];
                f32x4 fv = acc[nj + 2][rf];
                f32x4 gv = acc[nj + 4][rf];
                f32x4 ov = acc[nj + 6][rf];
                const size_t cidx = ((((size_t)tile * 4 + w) * 2 + nj) * 2 + rf) * 64 + l;
                float cold[4];
                if (FIRST) {
                    cold[0] = cold[1] = cold[2] = cold[3] = 0.f;
                } else {
                    half4 ch = cperm[cidx];
#pragma unroll
                    for (int jj = 0; jj < 4; ++jj) cold[jj] = (float)ch[jj];
                }
                half4 cw;
                float hn[4];
#pragma unroll
                for (int jj = 0; jj < 4; ++jj) {
                    float c2 = sigf(fv[jj]) * cold[jj] + sigf(iv[jj]) * tanh_fast(gv[jj]);
                    cw[jj] = (_Float16)c2;
                    hn[jj] = sigf(ov[jj]) * tanh_fast(c2);
                }
                cperm[cidx] = cw;
                const int rbase = rf * 16 + lk * 4;
#pragma unroll
                for (int jj = 0; jj < 4; ++jj)
                    lds_h[(rbase + jj) * 136 + col] = f2bf(hn[jj]);
            }
        }
        __syncthreads();
        // coalesced h store: thread t moves 16 ushorts: row t>>3, cols (t&7)*16..+15
        {
            const ushort* lsrc = &lds_h[(t >> 3) * 136 + (t & 7) * 16];
            short8 v0 = *reinterpret_cast<const short8*>(lsrc);
            short8 v1 = *reinterpret_cast<const short8*>(lsrc + 8);
            ushort* gdst = hout + (size_t)row0 * HID + t * 16;
            *reinterpret_cast<short8*>(gdst) = v0;
            *reinterpret_cast<short8*>(gdst + 8) = v1;
        }
    }
}

// ---------------------------------------------------------------------------
// SpMM (r14 best: ~125us/hop): one wave per row, lane owns 2 features (dword
// gather), 8-edge-deep MLP, nontemporal edge stream. FROZEN — 16-deep and all
// locality schemes measured worse.
// ---------------------------------------------------------------------------
__global__ __launch_bounds__(256) void spmm_kernel(
    const int* __restrict__ rp, const ull* __restrict__ epack,
    const ushort* __restrict__ hin, ushort* __restrict__ hout)
{
    int r = blockIdx.x * 4 + (threadIdx.x >> 6);
    if (r >= NN) return;
    int l = threadIdx.x & 63;
    int beg = rp[r], end = rp[r + 1];
    const ushort* hbase = hin + l * 2;

    float s0a = 0.f, s1a = 0.f, s0b = 0.f, s1b = 0.f;
    float s0c = 0.f, s1c = 0.f, s0d = 0.f, s1d = 0.f;
    float s0e = 0.f, s1e = 0.f, s0f = 0.f, s1f = 0.f;
    float s0g = 0.f, s1g = 0.f, s0h = 0.f, s1h = 0.f;
    int e = beg;
    for (; e + 8 <= end; e += 8) {
        ull u0 = __builtin_nontemporal_load(epack + e);
        ull u1 = __builtin_nontemporal_load(epack + e + 1);
        ull u2 = __builtin_nontemporal_load(epack + e + 2);
        ull u3 = __builtin_nontemporal_load(epack + e + 3);
        ull u4 = __builtin_nontemporal_load(epack + e + 4);
        ull u5 = __builtin_nontemporal_load(epack + e + 5);
        ull u6 = __builtin_nontemporal_load(epack + e + 6);
        ull u7 = __builtin_nontemporal_load(epack + e + 7);
        uint g0 = *reinterpret_cast<const uint*>(hbase + (size_t)(uint)u0 * HID);
        uint g1 = *reinterpret_cast<const uint*>(hbase + (size_t)(uint)u1 * HID);
        uint g2 = *reinterpret_cast<const uint*>(hbase + (size_t)(uint)u2 * HID);
        uint g3 = *reinterpret_cast<const uint*>(hbase + (size_t)(uint)u3 * HID);
        uint g4 = *reinterpret_cast<const uint*>(hbase + (size_t)(uint)u4 * HID);
        uint g5 = *reinterpret_cast<const uint*>(hbase + (size_t)(uint)u5 * HID);
        uint g6 = *reinterpret_cast<const uint*>(hbase + (size_t)(uint)u6 * HID);
        uint g7 = *reinterpret_cast<const uint*>(hbase + (size_t)(uint)u7 * HID);
        float v0 = __builtin_bit_cast(float, (uint)(u0 >> 32));
        float v1 = __builtin_bit_cast(float, (uint)(u1 >> 32));
        float v2 = __builtin_bit_cast(float, (uint)(u2 >> 32));
        float v3 = __builtin_bit_cast(float, (uint)(u3 >> 32));
        float v4 = __builtin_bit_cast(float, (uint)(u4 >> 32));
        float v5 = __builtin_bit_cast(float, (uint)(u5 >> 32));
        float v6 = __builtin_bit_cast(float, (uint)(u6 >> 32));
        float v7 = __builtin_bit_cast(float, (uint)(u7 >> 32));
        s0a += v0 * bflo(g0); s1a += v0 * bfhi(g0);
        s0b += v1 * bflo(g1); s1b += v1 * bfhi(g1);
        s0c += v2 * bflo(g2); s1c += v2 * bfhi(g2);
        s0d += v3 * bflo(g3); s1d += v3 * bfhi(g3);
        s0e += v4 * bflo(g4); s1e += v4 * bfhi(g4);
        s0f += v5 * bflo(g5); s1f += v5 * bfhi(g5);
        s0g += v6 * bflo(g6); s1g += v6 * bfhi(g6);
        s0h += v7 * bflo(g7); s1h += v7 * bfhi(g7);
    }
    for (; e + 4 <= end; e += 4) {
        ull u0 = __builtin_nontemporal_load(epack + e);
        ull u1 = __builtin_nontemporal_load(epack + e + 1);
        ull u2 = __builtin_nontemporal_load(epack + e + 2);
        ull u3 = __builtin_nontemporal_load(epack + e + 3);
        uint g0 = *reinterpret_cast<const uint*>(hbase + (size_t)(uint)u0 * HID);
        uint g1 = *reinterpret_cast<const uint*>(hbase + (size_t)(uint)u1 * HID);
        uint g2 = *reinterpret_cast<const uint*>(hbase + (size_t)(uint)u2 * HID);
        uint g3 = *reinterpret_cast<const uint*>(hbase + (size_t)(uint)u3 * HID);
        float v0 = __builtin_bit_cast(float, (uint)(u0 >> 32));
        float v1 = __builtin_bit_cast(float, (uint)(u1 >> 32));
        float v2 = __builtin_bit_cast(float, (uint)(u2 >> 32));
        float v3 = __builtin_bit_cast(float, (uint)(u3 >> 32));
        s0a += v0 * bflo(g0); s1a += v0 * bfhi(g0);
        s0b += v1 * bflo(g1); s1b += v1 * bfhi(g1);
        s0c += v2 * bflo(g2); s1c += v2 * bfhi(g2);
        s0d += v3 * bflo(g3); s1d += v3 * bfhi(g3);
    }
    for (; e < end; ++e) {
        ull u0 = __builtin_nontemporal_load(epack + e);
        float v0 = __builtin_bit_cast(float, (uint)(u0 >> 32));
        uint g0 = *reinterpret_cast<const uint*>(hbase + (size_t)(uint)u0 * HID);
        s0a += v0 * bflo(g0); s1a += v0 * bfhi(g0);
    }
    float s0 = ((s0a + s0b) + (s0c + s0d)) + ((s0e + s0f) + (s0g + s0h));
    float s1 = ((s1a + s1b) + (s1c + s1d)) + ((s1e + s1f) + (s1g + s1h));
    uint o = ((uint)f2bf(s1) << 16) | (uint)f2bf(s0);
    *reinterpret_cast<uint*>(hout + (size_t)r * HID + l * 2) = o;
}

// ---------------------------------------------------------------------------
// final: out = relu(h) @ fc_w^T + fc_b  (MFMA)
// ---------------------------------------------------------------------------
__global__ __launch_bounds__(256) void final_mfma_kernel(
    const ushort* __restrict__ hb, const ushort* __restrict__ fcwb,
    const float* __restrict__ fcb, float* __restrict__ out)
{
    const int t = threadIdx.x;
    const int l = t & 63;
    const int w = t >> 6;
    const int lr = l & 15;
    const int lk = l >> 4;
    const int row0 = blockIdx.x * 64 + w * 16;

    f32x4 acc[4];
#pragma unroll
    for (int n = 0; n < 4; ++n) {
        float b = fcb[n * 16 + lr];
        acc[n] = f32x4{b, b, b, b};
    }

    const short8 z8 = {0, 0, 0, 0, 0, 0, 0, 0};
    const int arow = row0 + lr;
    const bool aok = arow < NN;
    short8 a[4];
#pragma unroll
    for (int ks = 0; ks < 4; ++ks) {
        short8 v = aok ? load_frag(hb + (size_t)arow * HID + ks * 32 + lk * 8) : z8;
#pragma unroll
        for (int i = 0; i < 8; ++i) {
            ushort u = (ushort)v[i];
            if (u & 0x8000) v[i] = 0;   // relu in bf16
        }
        a[ks] = v;
    }

#pragma unroll
    for (int n = 0; n < 4; ++n) {
        const ushort* wp = fcwb + (size_t)(n * 16 + lr) * HID + lk * 8;
#pragma unroll
        for (int ks = 0; ks < 4; ++ks)
            acc[n] = mfma16(a[ks], load_frag(wp + ks * 32), acc[n]);
    }

#pragma unroll
    for (int n = 0; n < 4; ++n) {
#pragma unroll
        for (int j = 0; j < 4; ++j) {
            int row = row0 + lk * 4 + j;
            if (row < NN) out[(size_t)row * NOUT + n * 16 + lr] = acc[n][j];
        }
    }
}

// ---------------------------------------------------------------------------
extern "C" void kernel_launch(void* const* d_in, const int* in_sizes, int n_in,
                              void* d_out, int out_size, void* d_ws, size_t ws_size,
                              hipStream_t stream)
{
    const float* x    = (const float*)d_in[0];
    const int*   erow = (const int*)d_in[1];
    const int*   ecol = (const int*)d_in[2];
    const float* eval = (const float*)d_in[3];
    const float* Wih  = (const float*)d_in[4];
    const float* Whh  = (const float*)d_in[5];
    const float* bih  = (const float*)d_in[6];
    const float* bhh  = (const float*)d_in[7];
    const float* fcw  = (const float*)d_in[8];
    const float* fcb  = (const float*)d_in[9];
    float* out = (float*)d_out;

    char* ws = (char*)d_ws;
    size_t off = 0;
    auto alloc = [&](size_t bytes) -> void* {
        void* p = ws + off;
        off = (off + bytes + 255) & ~(size_t)255;
        return p;
    };
    ushort* hb_a  = (ushort*)alloc((size_t)NN * HID * 2);
    ushort* hb_b  = (ushort*)alloc((size_t)NN * HID * 2);
    half4*  cperm = (half4*)alloc(CPERM_SLOTS * 8);
    ushort* xb    = (ushort*)alloc((size_t)NN * HID * 2);
    ushort* Wib   = (ushort*)alloc((size_t)NG * HID * 2);
    ushort* Whb   = (ushort*)alloc((size_t)NG * HID * 2);
    ushort* fcwb  = (ushort*)alloc((size_t)NOUT * HID * 2);
    float*  bsum  = (float*)alloc((size_t)NG * 4);
    int*    rp    = (int*)alloc((size_t)(NN + 1) * 4);
    int*    deg   = (int*)alloc((size_t)NN * 4);
    int*    cur   = (int*)alloc((size_t)NN * 4);
    int*    bsums = (int*)alloc((size_t)NBLK_SCAN * 4);
    ull*    epack = (ull*)alloc((size_t)EE * 8);
    (void)ws_size;

    // conversions to bf16
    convert_bf16_kernel<<<(NN * HID / 4 + 255) / 256, 256, 0, stream>>>(x, xb, NN * HID / 4);
    convert_bf16_kernel<<<(NG * HID / 4 + 255) / 256, 256, 0, stream>>>(Wih, Wib, NG * HID / 4);
    convert_bf16_kernel<<<(NG * HID / 4 + 255) / 256, 256, 0, stream>>>(Whh, Whb, NG * HID / 4);
    convert_bf16_kernel<<<(NOUT * HID / 4 + 255) / 256, 256, 0, stream>>>(fcw, fcwb, NOUT * HID / 4);
    bsum_kernel<<<2, 256, 0, stream>>>(bih, bhh, bsum);

    // CSR build
    hipMemsetAsync(deg, 0, (size_t)NN * 4, stream);
    hist_kernel<<<EE / 256, 256, 0, stream>>>(erow, deg);
    scan1_kernel<<<NBLK_SCAN, SCAN_BLK, 0, stream>>>(deg, bsums);
    scan2_kernel<<<1, 128, 0, stream>>>(bsums);
    scan3_kernel<<<NBLK_SCAN, SCAN_BLK, 0, stream>>>(deg, bsums, rp, cur);
    scatter_kernel<<<EE / 256, 256, 0, stream>>>(erow, ecol, eval, cur, epack);

    const int SPMM_GRID = NN / 4;          // 25000

    cell_kernel<true><<<PERSIST, 256, 0, stream>>>(xb, hb_b, Wib, Whb, bsum, cperm, hb_a);
    spmm_kernel<<<SPMM_GRID, 256, 0, stream>>>(rp, epack, hb_a, hb_b);
    for (int hop = 1; hop < HOPS; ++hop) {
        cell_kernel<false><<<PERSIST, 256, 0, stream>>>(xb, hb_b, Wib, Whb, bsum, cperm, hb_a);
        spmm_kernel<<<SPMM_GRID, 256, 0, stream>>>(rp, epack, hb_a, hb_b);
    }

    final_mfma_kernel<<<(NN + 63) / 64, 256, 0, stream>>>(hb_b, fcwb, fcb, out);
}